// Round 13
// baseline (4477.827 us; speedup 1.0000x reference)
//
#include <hip/hip_runtime.h>
#include <hip/hip_bf16.h>

// SenseMemAct: sense Linear -> nBRC scan (L=1024) -> actor Linear -> softmax
// R27 = R25 (best, 2843us) + ack-free tagged publish.
//  - R26 post-mortem: R25 already overlapped produce/consume post-barrier;
//    moving iproj to wave3 just lengthened the consumer chain (44 MFMA/11
//    loads per wave) -> +11%. Fully reverted to R25's wave layout.
//  - New: hbuf slot = 16B [d0|tag|d1|tag] (R19 format; R21/R23 verified
//    addressing). Producer publishes data + flag with NO vmcnt ack between
//    (the ~300-600cy ack leaves the flag-visibility chain). Ordering safety:
//    consumer verifies embedded tags after its MALL poll; a racing in-flight
//    data store shows a stale tag -> rare fence+reload loop. R23 proved
//    consumers always arrive after producers (its unfenced attempt-1 never
//    passed) -> post-poll tag checks pass on first try in steady state.
//  - Everything else R25-verbatim: 4 waves consume 8 members each (poll ->
//    16 tagged loads -> 32 MFMA -> mpart), raw lgkm-only barrier, wave3
//    ew+publish post-barrier, iproj on waves 0-2 (2-step input prefetch),
//    pure-MALL poll, per-RING acquire fence (RING=8 with tagged layout).

#define B_TOT 64
#define L_SEQ 1024
#define N_IN 64
#define INSZ 128
#define MEM 1024
#define DEC 3

#define NGROUP 8
#define BG 8
#define NMEM 32
#define RING 8

typedef __hip_bfloat16 bf16;
typedef short bf16x8 __attribute__((ext_vector_type(8)));
typedef float f32x4 __attribute__((ext_vector_type(4)));
typedef int i32x4 __attribute__((ext_vector_type(4)));
typedef unsigned long long ull;

// ---- workspace layout (bytes) ----
#define OFF_INPUTS 0
#define SZ_INPUTS  (L_SEQ * 64 * INSZ * 2)                 // 16 MB (bf16)
#define OFF_WMM    (OFF_INPUTS + SZ_INPUTS)
#define SZ_WMM     (128 * 32 * 64 * 8 * 2)                 // 4 MB
#define OFF_WIM    (OFF_WMM + SZ_WMM)
#define SZ_WIM     (192 * 4 * 64 * 8 * 2)                  // 0.75 MB
#define OFF_HBUF   (OFF_WIM + SZ_WIM)
#define SZ_HBUF    (RING * NGROUP * NMEM * 1024)           // 2 MB (tagged)
#define OFF_CTR    (OFF_HBUF + SZ_HBUF)
#define SZ_CTR     ((4096 + 256) * 4)   // MALL flags | ids

__device__ __forceinline__ float fast_tanh(float x) {
    float e = __expf(2.f * x);
    return 1.f - 2.f / (e + 1.f);
}
__device__ __forceinline__ float fast_sigmoid(float x) {
    return 1.f / (1.f + __expf(-x));
}

// ---------------- sense: inputs = x @ W_sense + b_sense ----------------
__global__ void k_sense(const float* __restrict__ x, const float* __restrict__ Ws,
                        const float* __restrict__ bs, bf16* __restrict__ inputs) {
    int t = blockIdx.x;
    int tid = threadIdx.x;
    __shared__ float xls[64][64];
    __shared__ float wls[64][128];
    for (int idx = tid; idx < 64 * 64; idx += 256) {
        int b = idx >> 6, k = idx & 63;
        xls[b][k] = x[((size_t)b * L_SEQ + t) * N_IN + k];
    }
    for (int idx = tid; idx < 64 * 128; idx += 256) {
        int k = idx >> 7, j = idx & 127;
        wls[k][j] = Ws[k * INSZ + j];
    }
    __syncthreads();
    int j = tid & 127;
    int bh = tid >> 7;
    float bj = bs[j];
    for (int bi = 0; bi < 32; ++bi) {
        int b = bh * 32 + bi;
        float acc = bj;
#pragma unroll
        for (int k = 0; k < 64; ++k) acc += xls[b][k] * wls[k][j];
        inputs[((size_t)t * 64 + b) * INSZ + j] = (bf16)acc;
    }
}

// ---------------- pack weights into bf16 MFMA B-fragment order ----------------
// frag element (ct, kb, lane, j): n = ct*16 + (lane&15); k = kb*32 + (lane>>4)*8 + j
__global__ void k_pack(const float* __restrict__ Wmm, const float* __restrict__ Wim,
                       bf16* __restrict__ pmm, bf16* __restrict__ pim) {
    int idx = blockIdx.x * 256 + threadIdx.x;
    const int NMMF = 128 * 32 * 64 * 8;  // 2097152
    if (idx < NMMF) {
        int j = idx & 7, lane = (idx >> 3) & 63, kb = (idx >> 9) & 31, ct = idx >> 14;
        int n = ct * 16 + (lane & 15);
        int k = kb * 32 + ((lane >> 4) << 3) + j;
        pmm[idx] = (bf16)Wmm[(size_t)k * 2048 + n];
    } else {
        int idx2 = idx - NMMF;
        if (idx2 < 192 * 4 * 64 * 8) {
            int j = idx2 & 7, lane = (idx2 >> 3) & 63, kb = (idx2 >> 9) & 3, ct = idx2 >> 11;
            int n = ct * 16 + (lane & 15);
            int k = kb * 32 + ((lane >> 4) << 3) + j;
            pim[idx2] = (bf16)Wim[(size_t)k * 3072 + n];
        }
    }
}

// ---------------- persistent recurrent kernel ----------------
__launch_bounds__(256, 1)
__global__ void k_main(const bf16* __restrict__ inputs, const bf16* __restrict__ pmm,
                       const bf16* __restrict__ pim, const float* __restrict__ Wact,
                       const float* __restrict__ bact, bf16* __restrict__ hbuf,
                       float* __restrict__ out, unsigned int* __restrict__ ctr) {
    const int g = blockIdx.x & 7;       // group (8 batches); one XCD under %8 rr
    const int m = blockIdx.x >> 3;      // member (32 h-cols), 0..31
    const int tid = (int)threadIdx.x;
    const int wave = tid >> 6;
    const int lane = tid & 63;
    const int r16 = lane & 15;          // A-row / B-col within tile
    const int q = lane >> 4;            // quad
    const int slotA = (r16 & 7) * 8 + 2 * q;   // first of two A-frag slots

    __shared__ float ilds[2][3][2][8][16];   // buf, gate, tile, batch, col
    __shared__ float mpart[2][4][4][8][16];  // par, wave, tile(a0,a1,c0,c1), b, col
    __shared__ float wact_lds[3072];         // [1024 cols][3] row-major, f32x4-read
    __shared__ float aplds[2][4][3];         // par, wave, dec
    __shared__ float bactl[3];
    __shared__ unsigned idsl[256];
    __shared__ int fflagl;
    __shared__ float outbuf[L_SEQ * 3];      // deferred outputs (m<8 WGs), 12KB

    for (int idx = tid; idx < 3072; idx += 256) wact_lds[idx] = Wact[idx];
    if (tid < 3) bactl[tid] = bact[tid];

    // W_mm fragments, register-resident. Member owns h-cols [m*32, m*32+32):
    // output tiles ct = {2m, 2m+1} (a-half) and {64+2m, 65+2m} (c-half).
    // Wave w covers K-chunks kb = 8w .. 8w+7 (K = [256w, 256w+256)).
    bf16x8 wb[4][8];
    {
        int base_ct[4] = {2 * m, 2 * m + 1, 64 + 2 * m, 65 + 2 * m};
#pragma unroll
        for (int t4 = 0; t4 < 4; ++t4)
#pragma unroll
            for (int kk = 0; kk < 8; ++kk)
                wb[t4][kk] = *(const bf16x8*)(pmm +
                    (((size_t)base_ct[t4] * 32 + (wave * 8 + kk)) * 64 + lane) * 8);
    }
    bf16x8 wi[2][4];
    if (wave < 3) {
#pragma unroll
        for (int tl = 0; tl < 2; ++tl) {
            int ct2 = wave * 64 + m * 2 + tl;
#pragma unroll
            for (int kb2 = 0; kb2 < 4; ++kb2)
                wi[tl][kb2] = *(const bf16x8*)(pim + (((size_t)ct2 * 4 + kb2) * 64 + lane) * 8);
        }
    }

    // wave3 h state: lane = row(lane>>3) * 8 + colquad(lane&7)
    f32x4 hreg = {0.f, 0.f, 0.f, 0.f};
    const int erow = lane >> 3;
    const int ec = lane & 7;
    const int ep = ec >> 2;
    const int ecl = (ec & 3) * 4;

    // MALL flags: one 64B line (16 uints) per member; agent scope
    unsigned int* flags = ctr + g * 512;
    unsigned int* ids   = ctr + 4096;

    // ---- XCD uniformity handshake (once): picks data-publish mode ----
    unsigned xid;
    asm volatile("s_getreg_b32 %0, hwreg(HW_REG_XCC_ID)" : "=s"(xid));
    if (tid == 0)
        __hip_atomic_store(&ids[g * 32 + m], xid + 1u, __ATOMIC_RELAXED,
                           __HIP_MEMORY_SCOPE_AGENT);
    if (wave == 0) {
        int sb = 1 << 20;
        unsigned v0 = 0, v1 = 0, v2 = 0, v3 = 0;
        bool all = false;
        while (!all && --sb > 0) {
            v0 = __hip_atomic_load(&ids[lane], __ATOMIC_RELAXED, __HIP_MEMORY_SCOPE_AGENT);
            v1 = __hip_atomic_load(&ids[64 + lane], __ATOMIC_RELAXED, __HIP_MEMORY_SCOPE_AGENT);
            v2 = __hip_atomic_load(&ids[128 + lane], __ATOMIC_RELAXED, __HIP_MEMORY_SCOPE_AGENT);
            v3 = __hip_atomic_load(&ids[192 + lane], __ATOMIC_RELAXED, __HIP_MEMORY_SCOPE_AGENT);
            all = (bool)__all((int)(v0 && v1 && v2 && v3));
        }
        idsl[lane] = v0; idsl[64 + lane] = v1; idsl[128 + lane] = v2; idsl[192 + lane] = v3;
    }
    __syncthreads();
    if (tid == 0) {
        int f = 1;
        for (int g2 = 0; g2 < 8; ++g2) {
            unsigned r = idsl[g2 * 32];
            for (int k2 = 1; k2 < 32; ++k2) f &= (idsl[g2 * 32 + k2] == r);
        }
        fflagl = f;
    }
    __syncthreads();
    const bool fastf = (fflagl != 0);

    // ---- input-projection pipeline: loads issued 2 steps early ----
    bf16x8 afin[4];
    auto load_in = [&](int t) {
        if (wave < 3) {
            int brow = g * 8 + (r16 & 7);
            const bf16* src = inputs + ((size_t)t * 64 + brow) * INSZ + q * 8;
#pragma unroll
            for (int kb2 = 0; kb2 < 4; ++kb2)
                afin[kb2] = *(const bf16x8*)(src + kb2 * 32);
        }
    };
    auto mma_in_deposit = [&](int t) {
        if (wave < 3) {
            f32x4 a0 = (f32x4){0.f, 0.f, 0.f, 0.f};
            f32x4 a1 = (f32x4){0.f, 0.f, 0.f, 0.f};
#pragma unroll
            for (int kb2 = 0; kb2 < 4; ++kb2) {
                a0 = __builtin_amdgcn_mfma_f32_16x16x32_bf16(afin[kb2], wi[0][kb2], a0, 0, 0, 0);
                a1 = __builtin_amdgcn_mfma_f32_16x16x32_bf16(afin[kb2], wi[1][kb2], a1, 0, 0, 0);
            }
            if (q < 2) {
#pragma unroll
                for (int reg = 0; reg < 4; ++reg) {
                    ilds[t & 1][wave][0][q * 4 + reg][r16] = a0[reg];
                    ilds[t & 1][wave][1][q * 4 + reg][r16] = a1[reg];
                }
            }
        }
    };

    // poll this wave's 8 producers: pure MALL rounds (settled protocol)
    auto poll_own = [&](unsigned target) {
        int k = wave * 8 + (lane & 7);
        bool act = lane < 8;
        unsigned vbest = act ? 0u : target;
        int rounds = 0;
        int sb = 1 << 18;                // hang-guard only
        while (--sb > 0) {
            if (act && vbest < target) {
                unsigned vm = __hip_atomic_load(&flags[k * 16], __ATOMIC_RELAXED,
                                                __HIP_MEMORY_SCOPE_AGENT);
                if (vm > vbest) vbest = vm;
            }
            if (__all((int)(vbest >= target))) break;
            if (++rounds > 8) __builtin_amdgcn_s_sleep(1);
        }
    };

    // ---- actor helpers (waves 0-2 only); tagged layout, data dwords x,z ----
    auto hload = [&](int t_src, int gg) -> ull {
        int c0 = gg * 4;
        const char* ap = (const char*)hbuf +
            ((size_t)(((t_src & (RING - 1)) * NGROUP + g)) * (NMEM * 1024)) +
            (size_t)(c0 >> 5) * 1024 + ((size_t)(m * 8 + ((c0 >> 2) & 7))) * 16;
        i32x4 l = *(const i32x4*)ap;
        return (ull)(unsigned)l.x | ((ull)(unsigned)l.z << 32);
    };
    auto emit_accum = [&](ull hv, int gg, float& p0, float& p1, float& p2) {
        int c0 = gg * 4;
        float h0 = __uint_as_float(((unsigned)hv & 0xffffu) << 16);
        float h1 = __uint_as_float((unsigned)hv & 0xffff0000u);
        float h2 = __uint_as_float(((unsigned)(hv >> 32) & 0xffffu) << 16);
        float h3 = __uint_as_float((unsigned)(hv >> 48) << 16);
        const f32x4* wp = (const f32x4*)&wact_lds[c0 * 3];
        f32x4 w0 = wp[0], w1 = wp[1], w2 = wp[2];
        p0 += h0 * w0[0] + h1 * w0[3] + h2 * w1[2] + h3 * w2[1];
        p1 += h0 * w0[1] + h1 * w1[0] + h2 * w1[3] + h3 * w2[2];
        p2 += h0 * w0[2] + h1 * w1[1] + h2 * w2[0] + h3 * w2[3];
    };
    auto emit_reduce = [&](int t_src, float p0, float p1, float p2) {
#pragma unroll
        for (int off = 32; off >= 1; off >>= 1) {
            p0 += __shfl_xor(p0, off);
            p1 += __shfl_xor(p1, off);
            p2 += __shfl_xor(p2, off);
        }
        if (lane == 0) {
            aplds[t_src & 1][wave][0] = p0;
            aplds[t_src & 1][wave][1] = p1;
            aplds[t_src & 1][wave][2] = p2;
        }
    };
    auto fin = [&](int tout) {
        int pr = tout & 1;
        float l0 = aplds[pr][0][0] + aplds[pr][1][0] + aplds[pr][2][0] + bactl[0];
        float l1 = aplds[pr][0][1] + aplds[pr][1][1] + aplds[pr][2][1] + bactl[1];
        float l2 = aplds[pr][0][2] + aplds[pr][1][2] + aplds[pr][2][2] + bactl[2];
        float mx = fmaxf(l0, fmaxf(l1, l2));
        float e0 = __expf(l0 - mx), e1 = __expf(l1 - mx), e2 = __expf(l2 - mx);
        float inv = 1.f / (e0 + e1 + e2);
        outbuf[tout * 3 + 0] = e0 * inv;
        outbuf[tout * 3 + 1] = e1 * inv;
        outbuf[tout * 3 + 2] = e2 * inv;
    };

    // ---- wave3: fused K-reduce + nBRC ew + ACK-FREE tagged publish ----
    auto ew_publish = [&](int t) {
        int par = t & 1;
        f32x4 ma = *(const f32x4*)&mpart[par][0][ep][erow][ecl];
        f32x4 mc = *(const f32x4*)&mpart[par][0][2 + ep][erow][ecl];
#pragma unroll
        for (int w = 1; w < 4; ++w) {
            ma += *(const f32x4*)&mpart[par][w][ep][erow][ecl];
            mc += *(const f32x4*)&mpart[par][w][2 + ep][erow][ecl];
        }
        f32x4 ia = *(const f32x4*)&ilds[par][0][ep][erow][ecl];
        f32x4 ic = *(const f32x4*)&ilds[par][1][ep][erow][ecl];
        f32x4 io = *(const f32x4*)&ilds[par][2][ep][erow][ecl];
        bf16 hb[4];
#pragma unroll
        for (int i = 0; i < 4; ++i) {
            float a = 1.f + fast_tanh(ia[i] + ma[i]);
            float c = fast_sigmoid(ic[i] + mc[i]);
            float hn = c * hreg[i] + (1.f - c) * fast_tanh(io[i] + a * hreg[i]);
            hreg[i] = hn;
            hb[i] = (bf16)hn;
        }
        ull v = *(const ull*)hb;
        char* slotp = (char*)hbuf +
            ((size_t)(((t & (RING - 1)) * NGROUP + g)) * (NMEM * 1024)) +
            (size_t)m * 1024 + (size_t)lane * 16;
        unsigned lo = (unsigned)(v & 0xffffffffu);
        unsigned hi = (unsigned)(v >> 32);
        if (fastf) {
            i32x4 pv;
            pv.x = (int)lo;
            pv.y = t + 1;        // tag guards first 8B half
            pv.z = (int)hi;
            pv.w = t + 1;        // tag guards second 8B half
            *(i32x4*)slotp = pv; // single store; NO ack -- tags carry ordering
        } else {
            __hip_atomic_store((unsigned*)slotp, lo, __ATOMIC_RELAXED,
                               __HIP_MEMORY_SCOPE_AGENT);
            __hip_atomic_store((unsigned*)(slotp + 8), hi, __ATOMIC_RELAXED,
                               __HIP_MEMORY_SCOPE_AGENT);
            asm volatile("s_waitcnt vmcnt(0)" ::: "memory");
            __hip_atomic_store((unsigned*)(slotp + 4), (unsigned)(t + 1),
                               __ATOMIC_RELAXED, __HIP_MEMORY_SCOPE_AGENT);
            __hip_atomic_store((unsigned*)(slotp + 12), (unsigned)(t + 1),
                               __ATOMIC_RELAXED, __HIP_MEMORY_SCOPE_AGENT);
        }
        if (lane == 0)
            __hip_atomic_store(&flags[m * 16], (unsigned)(t + 1), __ATOMIC_RELAXED,
                               __HIP_MEMORY_SCOPE_AGENT);   // MALL, authoritative
    };

    // prologue: i-proj for step 0; issue loads for step 1
    load_in(0);
    mma_in_deposit(0);
    load_in(1);

    ull eh0 = 0, eh1 = 0;

#pragma clang loop unroll(disable)
    for (int t = 0; t < L_SEQ; ++t) {
        // every RING steps drop stale L1 lines before slot reuse
        if (t != 0 && (t & (RING - 1)) == 0)
            __builtin_amdgcn_fence(__ATOMIC_ACQUIRE, "agent");

        // wait only for THIS wave's 8 producers (t=0 reads the zeroed slot)
        if (t > 0) poll_own((unsigned)t);

        // ---- tagged A-frag load + verify (ack-free publish safety) ----
        bf16x8 af[8];
        {
            const char* sb2 = (const char*)hbuf +
                ((size_t)(((t + RING - 1) & (RING - 1)) * NGROUP + g)) * (NMEM * 1024);
            const char* b0 = sb2 + (size_t)(wave * 8192) + (size_t)slotA * 16;
            i32x4 l[16];
            const unsigned tg = (unsigned)t;
#pragma unroll
            for (int i = 0; i < 16; ++i) {
                const char* a = b0 + (i >> 1) * 1024 + (i & 1) * 16;
                l[i] = *(const i32x4*)a;
            }
            bool ok = true;
#pragma unroll
            for (int i = 0; i < 16; ++i)
                ok &= ((unsigned)l[i].y == tg) & ((unsigned)l[i].w == tg);
            if (!__all((int)ok)) {
                // cold path: data store still in flight; fence + reload
                int rounds = 0;
                int sb = 1 << 17;
                while (--sb > 0) {
                    __builtin_amdgcn_fence(__ATOMIC_ACQUIRE, "agent");
#pragma unroll
                    for (int i = 0; i < 16; ++i) {
                        const char* a = b0 + (i >> 1) * 1024 + (i & 1) * 16;
                        l[i] = *(const i32x4*)a;
                    }
                    bool ok2 = true;
#pragma unroll
                    for (int i = 0; i < 16; ++i)
                        ok2 &= ((unsigned)l[i].y == tg) & ((unsigned)l[i].w == tg);
                    if (__all((int)ok2)) break;
                    if (++rounds > 8) __builtin_amdgcn_s_sleep(1);
                }
            }
            // slot dwords: x = cols j0,j1 ; z = cols j2,j3
#pragma unroll
            for (int kk = 0; kk < 8; ++kk) {
                i32x4 d;
                d.x = l[2 * kk].x;     d.y = l[2 * kk].z;
                d.z = l[2 * kk + 1].x; d.w = l[2 * kk + 1].z;
                af[kk] = *(bf16x8*)&d;
            }
        }

        // ---- m = H @ W_mm partials -> plain stores into mpart[t&1] ----
        {
            f32x4 acc0 = {0.f, 0.f, 0.f, 0.f};
            f32x4 acc1 = {0.f, 0.f, 0.f, 0.f};
            f32x4 acc2 = {0.f, 0.f, 0.f, 0.f};
            f32x4 acc3 = {0.f, 0.f, 0.f, 0.f};
#pragma unroll
            for (int kk = 0; kk < 8; ++kk) {
                acc0 = __builtin_amdgcn_mfma_f32_16x16x32_bf16(af[kk], wb[0][kk], acc0, 0, 0, 0);
                acc1 = __builtin_amdgcn_mfma_f32_16x16x32_bf16(af[kk], wb[1][kk], acc1, 0, 0, 0);
                acc2 = __builtin_amdgcn_mfma_f32_16x16x32_bf16(af[kk], wb[2][kk], acc2, 0, 0, 0);
                acc3 = __builtin_amdgcn_mfma_f32_16x16x32_bf16(af[kk], wb[3][kk], acc3, 0, 0, 0);
            }
            if (q < 2) {
                int par = t & 1;
#pragma unroll
                for (int reg = 0; reg < 4; ++reg) {
                    mpart[par][wave][0][q * 4 + reg][r16] = acc0[reg];
                    mpart[par][wave][1][q * 4 + reg][r16] = acc1[reg];
                    mpart[par][wave][2][q * 4 + reg][r16] = acc2[reg];
                    mpart[par][wave][3][q * 4 + reg][r16] = acc3[reg];
                }
            }
        }
        // actor h-prefetch: group tid -> member tid>>3 == this wave's polled set
        if (m < 8 && t > 0 && wave < 3) eh0 = hload(t - 1, tid);

        // raw barrier: LDS handoff needs only lgkmcnt(0); global prefetch
        // loads stay in flight (R25-proven)
        asm volatile("s_waitcnt lgkmcnt(0)\n\ts_barrier" ::: "memory");

        if (wave == 3) {
            ew_publish(t);   // reads mpart[t&1], ilds[t&1]; h in regs; publishes
        } else {
            if (m < 8 && t > 0 && wave == 0) eh1 = hload(t - 1, tid + 192);
            if (t + 1 < L_SEQ) mma_in_deposit(t + 1);   // consumes loads from t-1
            if (t + 2 < L_SEQ) load_in(t + 2);          // a full step to land
            if (m < 8) {
                if (t >= 2 && tid == 64) fin(t - 2);
                if (t > 0) {
                    float p0 = 0.f, p1 = 0.f, p2 = 0.f;
                    emit_accum(eh0, tid, p0, p1, p2);
                    if (wave == 0) emit_accum(eh1, tid + 192, p0, p1, p2);
                    emit_reduce(t - 1, p0, p1, p2);
                }
            }
        }
    }

    // epilogue: finish t = L-2, L-1, then bulk-write this batch's output
    if (m < 8) {
        __syncthreads();
        if (tid == 64) fin(L_SEQ - 2);
        poll_own((unsigned)L_SEQ);                 // all 32 slices of slot L-1
        __builtin_amdgcn_fence(__ATOMIC_ACQUIRE, "agent");
        __syncthreads();
        if (wave < 3) {
            float p0 = 0.f, p1 = 0.f, p2 = 0.f;
            ull a = hload(L_SEQ - 1, tid);
            emit_accum(a, tid, p0, p1, p2);
            if (wave == 0) {
                ull b = hload(L_SEQ - 1, tid + 192);
                emit_accum(b, tid + 192, p0, p1, p2);
            }
            emit_reduce(L_SEQ - 1, p0, p1, p2);
        }
        __syncthreads();
        if (tid == 0) fin(L_SEQ - 1);
        __syncthreads();
        float* obase = out + (size_t)(g * 8 + m) * L_SEQ * 3;
        for (int idx = tid; idx < L_SEQ * 3; idx += 256)
            obase[idx] = outbuf[idx];   // end-of-kernel release flushes
    }
}

extern "C" void kernel_launch(void* const* d_in, const int* in_sizes, int n_in,
                              void* d_out, int out_size, void* d_ws, size_t ws_size,
                              hipStream_t stream) {
    const float* x    = (const float*)d_in[0];
    const float* Ws   = (const float*)d_in[1];
    const float* bs   = (const float*)d_in[2];
    const float* Wim  = (const float*)d_in[3];
    const float* Wmm  = (const float*)d_in[4];
    const float* Wact = (const float*)d_in[5];
    const float* bact = (const float*)d_in[6];

    char* ws = (char*)d_ws;
    bf16* inputs = (bf16*)(ws + OFF_INPUTS);
    bf16* pmm    = (bf16*)(ws + OFF_WMM);
    bf16* pim    = (bf16*)(ws + OFF_WIM);
    bf16* hbuf   = (bf16*)(ws + OFF_HBUF);
    unsigned int* ctr = (unsigned int*)(ws + OFF_CTR);

    hipMemsetAsync(hbuf, 0, SZ_HBUF, stream);   // slot 7 zeros = H^{-1}, tags 0
    hipMemsetAsync(ctr, 0, SZ_CTR, stream);

    k_sense<<<L_SEQ, 256, 0, stream>>>(x, Ws, bs, inputs);
    k_pack<<<(128 * 32 * 64 * 8 + 192 * 4 * 64 * 8) / 256, 256, 0, stream>>>(Wmm, Wim, pmm, pim);
    k_main<<<NGROUP * NMEM, 256, 0, stream>>>(inputs, pmm, pim, Wact, bact, hbuf,
                                              (float*)d_out, ctr);
}

// Round 14
// 2729.456 us; speedup vs baseline: 1.6406x; 1.6406x over previous
//
#include <hip/hip_runtime.h>
#include <hip/hip_bf16.h>

// SenseMemAct: sense Linear -> nBRC scan (L=1024) -> actor Linear -> softmax
// R28 = R25 verbatim (session best: 2843us steady, 3025us dur).
// Final protocol map (HW-verified R16-R27):
//  - MALL agent-atomic flag poll: ONLY working+fast sync (others: sc0 never
//    observes remote stores; fence-per-poll 4-6x slow; tagged layouts double
//    consumer traffic; LDS atomicAdd reduce contends the critical path).
//  - Data via plain L2 stores/loads + per-RING acquire fence; publish =
//    data store -> vmcnt ack -> MALL flag (ack required: flag must imply
//    data-visible; tag-based ack removal traded 300cy hidden ack for
//    1000+cy exposed consumer work -- R27 regression).
//  - Raw {s_waitcnt lgkmcnt(0); s_barrier}: LDS handoff only needs lgkm;
//    global prefetch stays in flight across the barrier (R25's win).
//  - Step structure: 4 waves consume 8 members each (poll -> 8 A-frag loads
//    -> 32 MFMA -> mpart) | barrier | wave3 ew+publish overlapped with
//    waves 0-2 iproj(t+1)+input-load(t+2)+actor.
// Remaining gap to ideal is the per-step MALL RTT chain (~2.8us/step):
// a latency floor of the 32-member cross-WG decomposition, not a
// bandwidth/compute roofline (all utils <10%).

#define B_TOT 64
#define L_SEQ 1024
#define N_IN 64
#define INSZ 128
#define MEM 1024
#define DEC 3

#define NGROUP 8
#define BG 8
#define NMEM 32
#define RING 16

typedef __hip_bfloat16 bf16;
typedef short bf16x8 __attribute__((ext_vector_type(8)));
typedef float f32x4 __attribute__((ext_vector_type(4)));
typedef int i32x4 __attribute__((ext_vector_type(4)));
typedef unsigned long long ull;

// ---- workspace layout (bytes) ----
#define OFF_INPUTS 0
#define SZ_INPUTS  (L_SEQ * 64 * INSZ * 2)                 // 16 MB (bf16)
#define OFF_WMM    (OFF_INPUTS + SZ_INPUTS)
#define SZ_WMM     (128 * 32 * 64 * 8 * 2)                 // 4 MB
#define OFF_WIM    (OFF_WMM + SZ_WMM)
#define SZ_WIM     (192 * 4 * 64 * 8 * 2)                  // 0.75 MB
#define OFF_HBUF   (OFF_WIM + SZ_WIM)
#define SZ_HBUF    (RING * NGROUP * BG * MEM * 2)          // 2 MB
#define OFF_CTR    (OFF_HBUF + SZ_HBUF)
#define SZ_CTR     ((4096 + 256) * 4)   // MALL flags | ids

__device__ __forceinline__ float fast_tanh(float x) {
    float e = __expf(2.f * x);
    return 1.f - 2.f / (e + 1.f);
}
__device__ __forceinline__ float fast_sigmoid(float x) {
    return 1.f / (1.f + __expf(-x));
}

// ---------------- sense: inputs = x @ W_sense + b_sense ----------------
__global__ void k_sense(const float* __restrict__ x, const float* __restrict__ Ws,
                        const float* __restrict__ bs, bf16* __restrict__ inputs) {
    int t = blockIdx.x;
    int tid = threadIdx.x;
    __shared__ float xls[64][64];
    __shared__ float wls[64][128];
    for (int idx = tid; idx < 64 * 64; idx += 256) {
        int b = idx >> 6, k = idx & 63;
        xls[b][k] = x[((size_t)b * L_SEQ + t) * N_IN + k];
    }
    for (int idx = tid; idx < 64 * 128; idx += 256) {
        int k = idx >> 7, j = idx & 127;
        wls[k][j] = Ws[k * INSZ + j];
    }
    __syncthreads();
    int j = tid & 127;
    int bh = tid >> 7;
    float bj = bs[j];
    for (int bi = 0; bi < 32; ++bi) {
        int b = bh * 32 + bi;
        float acc = bj;
#pragma unroll
        for (int k = 0; k < 64; ++k) acc += xls[b][k] * wls[k][j];
        inputs[((size_t)t * 64 + b) * INSZ + j] = (bf16)acc;
    }
}

// ---------------- pack weights into bf16 MFMA B-fragment order ----------------
// frag element (ct, kb, lane, j): n = ct*16 + (lane&15); k = kb*32 + (lane>>4)*8 + j
__global__ void k_pack(const float* __restrict__ Wmm, const float* __restrict__ Wim,
                       bf16* __restrict__ pmm, bf16* __restrict__ pim) {
    int idx = blockIdx.x * 256 + threadIdx.x;
    const int NMMF = 128 * 32 * 64 * 8;  // 2097152
    if (idx < NMMF) {
        int j = idx & 7, lane = (idx >> 3) & 63, kb = (idx >> 9) & 31, ct = idx >> 14;
        int n = ct * 16 + (lane & 15);
        int k = kb * 32 + ((lane >> 4) << 3) + j;
        pmm[idx] = (bf16)Wmm[(size_t)k * 2048 + n];
    } else {
        int idx2 = idx - NMMF;
        if (idx2 < 192 * 4 * 64 * 8) {
            int j = idx2 & 7, lane = (idx2 >> 3) & 63, kb = (idx2 >> 9) & 3, ct = idx2 >> 11;
            int n = ct * 16 + (lane & 15);
            int k = kb * 32 + ((lane >> 4) << 3) + j;
            pim[idx2] = (bf16)Wim[(size_t)k * 3072 + n];
        }
    }
}

// ---------------- persistent recurrent kernel ----------------
__launch_bounds__(256, 1)
__global__ void k_main(const bf16* __restrict__ inputs, const bf16* __restrict__ pmm,
                       const bf16* __restrict__ pim, const float* __restrict__ Wact,
                       const float* __restrict__ bact, bf16* __restrict__ hbuf,
                       float* __restrict__ out, unsigned int* __restrict__ ctr) {
    const int g = blockIdx.x & 7;       // group (8 batches); one XCD under %8 rr
    const int m = blockIdx.x >> 3;      // member (32 h-cols), 0..31
    const int tid = (int)threadIdx.x;
    const int wave = tid >> 6;
    const int lane = tid & 63;
    const int r16 = lane & 15;          // A-row / B-col within tile
    const int q = lane >> 4;            // quad

    __shared__ float ilds[2][3][2][8][16];   // buf, gate, tile, batch, col
    __shared__ float mpart[2][4][4][8][16];  // par, wave, tile(a0,a1,c0,c1), b, col
    __shared__ float wact_lds[3072];         // [1024 cols][3] row-major, f32x4-read
    __shared__ float aplds[2][4][3];         // par, wave, dec
    __shared__ float bactl[3];
    __shared__ unsigned idsl[256];
    __shared__ int fflagl;
    __shared__ float outbuf[L_SEQ * 3];      // deferred outputs (m<8 WGs), 12KB

    for (int idx = tid; idx < 3072; idx += 256) wact_lds[idx] = Wact[idx];
    if (tid < 3) bactl[tid] = bact[tid];

    // W_mm fragments, register-resident. Member owns h-cols [m*32, m*32+32):
    // output tiles ct = {2m, 2m+1} (a-half) and {64+2m, 65+2m} (c-half).
    // Wave w covers K-chunks kb = 8w .. 8w+7 (K = [256w, 256w+256)).
    bf16x8 wb[4][8];
    {
        int base_ct[4] = {2 * m, 2 * m + 1, 64 + 2 * m, 65 + 2 * m};
#pragma unroll
        for (int t4 = 0; t4 < 4; ++t4)
#pragma unroll
            for (int kk = 0; kk < 8; ++kk)
                wb[t4][kk] = *(const bf16x8*)(pmm +
                    (((size_t)base_ct[t4] * 32 + (wave * 8 + kk)) * 64 + lane) * 8);
    }
    bf16x8 wi[2][4];
    if (wave < 3) {
#pragma unroll
        for (int tl = 0; tl < 2; ++tl) {
            int ct2 = wave * 64 + m * 2 + tl;
#pragma unroll
            for (int kb2 = 0; kb2 < 4; ++kb2)
                wi[tl][kb2] = *(const bf16x8*)(pim + (((size_t)ct2 * 4 + kb2) * 64 + lane) * 8);
        }
    }

    // wave3 h state: lane = row(lane>>3) * 8 + colquad(lane&7)
    f32x4 hreg = {0.f, 0.f, 0.f, 0.f};
    const int erow = lane >> 3;
    const int ec = lane & 7;
    const int ep = ec >> 2;
    const int ecl = (ec & 3) * 4;

    // MALL flags: one 64B line (16 uints) per member; agent scope
    unsigned int* flags = ctr + g * 512;
    unsigned int* ids   = ctr + 4096;

    // ---- XCD uniformity handshake (once): picks data-publish mode ----
    unsigned xid;
    asm volatile("s_getreg_b32 %0, hwreg(HW_REG_XCC_ID)" : "=s"(xid));
    if (tid == 0)
        __hip_atomic_store(&ids[g * 32 + m], xid + 1u, __ATOMIC_RELAXED,
                           __HIP_MEMORY_SCOPE_AGENT);
    if (wave == 0) {
        int sb = 1 << 20;
        unsigned v0 = 0, v1 = 0, v2 = 0, v3 = 0;
        bool all = false;
        while (!all && --sb > 0) {
            v0 = __hip_atomic_load(&ids[lane], __ATOMIC_RELAXED, __HIP_MEMORY_SCOPE_AGENT);
            v1 = __hip_atomic_load(&ids[64 + lane], __ATOMIC_RELAXED, __HIP_MEMORY_SCOPE_AGENT);
            v2 = __hip_atomic_load(&ids[128 + lane], __ATOMIC_RELAXED, __HIP_MEMORY_SCOPE_AGENT);
            v3 = __hip_atomic_load(&ids[192 + lane], __ATOMIC_RELAXED, __HIP_MEMORY_SCOPE_AGENT);
            all = (bool)__all((int)(v0 && v1 && v2 && v3));
        }
        idsl[lane] = v0; idsl[64 + lane] = v1; idsl[128 + lane] = v2; idsl[192 + lane] = v3;
    }
    __syncthreads();
    if (tid == 0) {
        int f = 1;
        for (int g2 = 0; g2 < 8; ++g2) {
            unsigned r = idsl[g2 * 32];
            for (int k2 = 1; k2 < 32; ++k2) f &= (idsl[g2 * 32 + k2] == r);
        }
        fflagl = f;
    }
    __syncthreads();
    const bool fastf = (fflagl != 0);

    // ---- input-projection pipeline: loads issued 2 steps early ----
    bf16x8 afin[4];
    auto load_in = [&](int t) {
        if (wave < 3) {
            int brow = g * 8 + (r16 & 7);
            const bf16* src = inputs + ((size_t)t * 64 + brow) * INSZ + q * 8;
#pragma unroll
            for (int kb2 = 0; kb2 < 4; ++kb2)
                afin[kb2] = *(const bf16x8*)(src + kb2 * 32);
        }
    };
    auto mma_in_deposit = [&](int t) {
        if (wave < 3) {
            f32x4 a0 = (f32x4){0.f, 0.f, 0.f, 0.f};
            f32x4 a1 = (f32x4){0.f, 0.f, 0.f, 0.f};
#pragma unroll
            for (int kb2 = 0; kb2 < 4; ++kb2) {
                a0 = __builtin_amdgcn_mfma_f32_16x16x32_bf16(afin[kb2], wi[0][kb2], a0, 0, 0, 0);
                a1 = __builtin_amdgcn_mfma_f32_16x16x32_bf16(afin[kb2], wi[1][kb2], a1, 0, 0, 0);
            }
            if (q < 2) {
#pragma unroll
                for (int reg = 0; reg < 4; ++reg) {
                    ilds[t & 1][wave][0][q * 4 + reg][r16] = a0[reg];
                    ilds[t & 1][wave][1][q * 4 + reg][r16] = a1[reg];
                }
            }
        }
    };

    // poll this wave's 8 producers: pure MALL rounds (settled protocol)
    auto poll_own = [&](unsigned target) {
        int k = wave * 8 + (lane & 7);
        bool act = lane < 8;
        unsigned vbest = act ? 0u : target;
        int rounds = 0;
        int sb = 1 << 18;                // hang-guard only
        while (--sb > 0) {
            if (act && vbest < target) {
                unsigned vm = __hip_atomic_load(&flags[k * 16], __ATOMIC_RELAXED,
                                                __HIP_MEMORY_SCOPE_AGENT);
                if (vm > vbest) vbest = vm;
            }
            if (__all((int)(vbest >= target))) break;
            if (++rounds > 8) __builtin_amdgcn_s_sleep(1);
        }
    };

    // ---- actor helpers (waves 0-2 only); plain L2 loads, per-RING fence ----
    auto hload = [&](int t_src, int gg) -> ushort4 {
        int c0 = gg * 4;
        const bf16* hp = hbuf +
            ((size_t)(((t_src & (RING - 1)) * NGROUP + g)) * (BG * MEM)) +
            (c0 >> 5) * 256 + m * 32 + (c0 & 31);
        return *(const ushort4*)hp;
    };
    auto emit_accum = [&](ushort4 hv, int gg, float& p0, float& p1, float& p2) {
        int c0 = gg * 4;
        float h0 = __uint_as_float((unsigned)hv.x << 16);
        float h1 = __uint_as_float((unsigned)hv.y << 16);
        float h2 = __uint_as_float((unsigned)hv.z << 16);
        float h3 = __uint_as_float((unsigned)hv.w << 16);
        const f32x4* wp = (const f32x4*)&wact_lds[c0 * 3];
        f32x4 w0 = wp[0], w1 = wp[1], w2 = wp[2];
        p0 += h0 * w0[0] + h1 * w0[3] + h2 * w1[2] + h3 * w2[1];
        p1 += h0 * w0[1] + h1 * w1[0] + h2 * w1[3] + h3 * w2[2];
        p2 += h0 * w0[2] + h1 * w1[1] + h2 * w2[0] + h3 * w2[3];
    };
    auto emit_reduce = [&](int t_src, float p0, float p1, float p2) {
#pragma unroll
        for (int off = 32; off >= 1; off >>= 1) {
            p0 += __shfl_xor(p0, off);
            p1 += __shfl_xor(p1, off);
            p2 += __shfl_xor(p2, off);
        }
        if (lane == 0) {
            aplds[t_src & 1][wave][0] = p0;
            aplds[t_src & 1][wave][1] = p1;
            aplds[t_src & 1][wave][2] = p2;
        }
    };
    auto fin = [&](int tout) {
        int pr = tout & 1;
        float l0 = aplds[pr][0][0] + aplds[pr][1][0] + aplds[pr][2][0] + bactl[0];
        float l1 = aplds[pr][0][1] + aplds[pr][1][1] + aplds[pr][2][1] + bactl[1];
        float l2 = aplds[pr][0][2] + aplds[pr][1][2] + aplds[pr][2][2] + bactl[2];
        float mx = fmaxf(l0, fmaxf(l1, l2));
        float e0 = __expf(l0 - mx), e1 = __expf(l1 - mx), e2 = __expf(l2 - mx);
        float inv = 1.f / (e0 + e1 + e2);
        outbuf[tout * 3 + 0] = e0 * inv;
        outbuf[tout * 3 + 1] = e1 * inv;
        outbuf[tout * 3 + 2] = e2 * inv;
    };

    // ---- wave3: fused K-reduce + nBRC ew + publish (straight-line) ----
    auto ew_publish = [&](int t) {
        int par = t & 1;
        f32x4 ma = *(const f32x4*)&mpart[par][0][ep][erow][ecl];
        f32x4 mc = *(const f32x4*)&mpart[par][0][2 + ep][erow][ecl];
#pragma unroll
        for (int w = 1; w < 4; ++w) {
            ma += *(const f32x4*)&mpart[par][w][ep][erow][ecl];
            mc += *(const f32x4*)&mpart[par][w][2 + ep][erow][ecl];
        }
        f32x4 ia = *(const f32x4*)&ilds[par][0][ep][erow][ecl];
        f32x4 ic = *(const f32x4*)&ilds[par][1][ep][erow][ecl];
        f32x4 io = *(const f32x4*)&ilds[par][2][ep][erow][ecl];
        bf16 hb[4];
#pragma unroll
        for (int i = 0; i < 4; ++i) {
            float a = 1.f + fast_tanh(ia[i] + ma[i]);
            float c = fast_sigmoid(ic[i] + mc[i]);
            float hn = c * hreg[i] + (1.f - c) * fast_tanh(io[i] + a * hreg[i]);
            hreg[i] = hn;
            hb[i] = (bf16)hn;
        }
        ull v = *(const ull*)hb;
        bf16* base = hbuf +
            ((size_t)(((t & (RING - 1)) * NGROUP + g)) * (BG * MEM)) + m * 256;
        ull* dst = (ull*)base + lane;
        if (fastf) {
            *dst = v;                       // write-through into shared XCD L2
        } else {
            __hip_atomic_store(dst, v, __ATOMIC_RELAXED, __HIP_MEMORY_SCOPE_AGENT);
        }
        asm volatile("s_waitcnt vmcnt(0)" ::: "memory");
        if (lane == 0)
            __hip_atomic_store(&flags[m * 16], (unsigned)(t + 1), __ATOMIC_RELAXED,
                               __HIP_MEMORY_SCOPE_AGENT);   // MALL, authoritative
    };

    // prologue: i-proj for step 0; issue loads for step 1
    load_in(0);
    mma_in_deposit(0);
    load_in(1);

    ushort4 eh0 = {0, 0, 0, 0}, eh1 = {0, 0, 0, 0};

#pragma clang loop unroll(disable)
    for (int t = 0; t < L_SEQ; ++t) {
        // every RING steps drop stale L1 lines before slot reuse
        if (t != 0 && (t & (RING - 1)) == 0)
            __builtin_amdgcn_fence(__ATOMIC_ACQUIRE, "agent");

        // wait only for THIS wave's 8 producers (t=0 reads the zeroed slot)
        if (t > 0) poll_own((unsigned)t);

        // A-frags direct from L2: member k's 512B block, rows 8..15 duplicate
        {
            const bf16* lp = hbuf +
                ((size_t)((((t + RING - 1) & (RING - 1)) * NGROUP + g)) * (BG * MEM)) +
                (size_t)(wave * 8) * 256 + ((r16 & 7) * 32 + q * 8);
            bf16x8 af[8];
#pragma unroll
            for (int kk = 0; kk < 8; ++kk)
                af[kk] = *(const bf16x8*)(lp + kk * 256);
            f32x4 acc0 = {0.f, 0.f, 0.f, 0.f};
            f32x4 acc1 = {0.f, 0.f, 0.f, 0.f};
            f32x4 acc2 = {0.f, 0.f, 0.f, 0.f};
            f32x4 acc3 = {0.f, 0.f, 0.f, 0.f};
#pragma unroll
            for (int kk = 0; kk < 8; ++kk) {
                acc0 = __builtin_amdgcn_mfma_f32_16x16x32_bf16(af[kk], wb[0][kk], acc0, 0, 0, 0);
                acc1 = __builtin_amdgcn_mfma_f32_16x16x32_bf16(af[kk], wb[1][kk], acc1, 0, 0, 0);
                acc2 = __builtin_amdgcn_mfma_f32_16x16x32_bf16(af[kk], wb[2][kk], acc2, 0, 0, 0);
                acc3 = __builtin_amdgcn_mfma_f32_16x16x32_bf16(af[kk], wb[3][kk], acc3, 0, 0, 0);
            }
            if (q < 2) {
                int par = t & 1;
#pragma unroll
                for (int reg = 0; reg < 4; ++reg) {
                    mpart[par][wave][0][q * 4 + reg][r16] = acc0[reg];
                    mpart[par][wave][1][q * 4 + reg][r16] = acc1[reg];
                    mpart[par][wave][2][q * 4 + reg][r16] = acc2[reg];
                    mpart[par][wave][3][q * 4 + reg][r16] = acc3[reg];
                }
            }
        }
        // actor h-prefetch: group tid -> member tid>>3 == this wave's polled set
        if (m < 8 && t > 0 && wave < 3) eh0 = hload(t - 1, tid);

        // raw barrier: LDS handoff needs only lgkmcnt(0); global prefetch
        // loads stay in flight (R25-proven)
        asm volatile("s_waitcnt lgkmcnt(0)\n\ts_barrier" ::: "memory");

        if (wave == 3) {
            ew_publish(t);   // reads mpart[t&1], ilds[t&1]; h in regs; publishes
        } else {
            if (m < 8 && t > 0 && wave == 0) eh1 = hload(t - 1, tid + 192);
            if (t + 1 < L_SEQ) mma_in_deposit(t + 1);   // consumes loads from t-1
            if (t + 2 < L_SEQ) load_in(t + 2);          // a full step to land
            if (m < 8) {
                if (t >= 2 && tid == 64) fin(t - 2);
                if (t > 0) {
                    float p0 = 0.f, p1 = 0.f, p2 = 0.f;
                    emit_accum(eh0, tid, p0, p1, p2);
                    if (wave == 0) emit_accum(eh1, tid + 192, p0, p1, p2);
                    emit_reduce(t - 1, p0, p1, p2);
                }
            }
        }
    }

    // epilogue: finish t = L-2, L-1, then bulk-write this batch's output
    if (m < 8) {
        __syncthreads();
        if (tid == 64) fin(L_SEQ - 2);
        poll_own((unsigned)L_SEQ);                 // all 32 slices of slot L-1
        __builtin_amdgcn_fence(__ATOMIC_ACQUIRE, "agent");
        __syncthreads();
        if (wave < 3) {
            float p0 = 0.f, p1 = 0.f, p2 = 0.f;
            ushort4 a = hload(L_SEQ - 1, tid);
            emit_accum(a, tid, p0, p1, p2);
            if (wave == 0) {
                ushort4 b = hload(L_SEQ - 1, tid + 192);
                emit_accum(b, tid + 192, p0, p1, p2);
            }
            emit_reduce(L_SEQ - 1, p0, p1, p2);
        }
        __syncthreads();
        if (tid == 0) fin(L_SEQ - 1);
        __syncthreads();
        float* obase = out + (size_t)(g * 8 + m) * L_SEQ * 3;
        for (int idx = tid; idx < L_SEQ * 3; idx += 256)
            obase[idx] = outbuf[idx];   // end-of-kernel release flushes
    }
}

extern "C" void kernel_launch(void* const* d_in, const int* in_sizes, int n_in,
                              void* d_out, int out_size, void* d_ws, size_t ws_size,
                              hipStream_t stream) {
    const float* x    = (const float*)d_in[0];
    const float* Ws   = (const float*)d_in[1];
    const float* bs   = (const float*)d_in[2];
    const float* Wim  = (const float*)d_in[3];
    const float* Wmm  = (const float*)d_in[4];
    const float* Wact = (const float*)d_in[5];
    const float* bact = (const float*)d_in[6];

    char* ws = (char*)d_ws;
    bf16* inputs = (bf16*)(ws + OFF_INPUTS);
    bf16* pmm    = (bf16*)(ws + OFF_WMM);
    bf16* pim    = (bf16*)(ws + OFF_WIM);
    bf16* hbuf   = (bf16*)(ws + OFF_HBUF);
    unsigned int* ctr = (unsigned int*)(ws + OFF_CTR);

    hipMemsetAsync(hbuf, 0, SZ_HBUF, stream);   // slot 15 zeros = H^{-1}
    hipMemsetAsync(ctr, 0, SZ_CTR, stream);

    k_sense<<<L_SEQ, 256, 0, stream>>>(x, Ws, bs, inputs);
    k_pack<<<(128 * 32 * 64 * 8 + 192 * 4 * 64 * 8) / 256, 256, 0, stream>>>(Wmm, Wim, pmm, pim);
    k_main<<<NGROUP * NMEM, 256, 0, stream>>>(inputs, pmm, pim, Wact, bact, hbuf,
                                              (float*)d_out, ctr);
}